// Round 4
// baseline (1038.251 us; speedup 1.0000x reference)
//
#include <hip/hip_runtime.h>
#include <hip/hip_bf16.h>

// Problem constants
#define PB   64          // batch
#define PT   100         // time steps
#define PH   128         // height
#define PW   128         // width
#define PF   1024        // pooled features = (128/4)*(128/4)
#define PM   (PB*PT)     // 6400 GEMM rows
#define PK   PF          // 1024
#define PN   200         // neurons
#define BETA1 0.95f
#define BETA2 0.9f

// ---------------- Kernel 1: fused 4x4 avg-pool + fp32 GEMM ----------------
// x: [B,T,128,128]  (A[m][k] = pooled feature k of image m, computed on the fly)
// W1: [200,1024], C(g1): [6400,200]
// BM=64 x BN=64 tile, BK=64. 400 blocks; the 4 n-siblings of an m-tile are
// placed on one XCD (swizzle) so their shared x-slice re-reads hit that L2.
//
// A-staging coalescing: pw = tid&31 is lane-fastest -> each 32-lane group
// reads one contiguous 512B image row per float4 instruction. Each thread
// sums the 16 pixels of one pooling window (4 float4 at row stride PW) and
// does a single LDS store. Summation order identical to the reference
// (row-major within window) -> bitwise-equal pooling.
#define BM 64
#define BN 64
#define BK 64
#define LPAD 4
__global__ __launch_bounds__(256) void fusedpool_gemm_kernel(const float* __restrict__ x,
                                                             const float* __restrict__ W1,
                                                             float* __restrict__ C) {
    __shared__ float Asl[BK][BM + LPAD];
    __shared__ float Wsl[BK][BN + LPAD];
    const int tid = threadIdx.x;

    // XCD-aware swizzle: 400 blocks, xcd = bid%8 (round-robin dispatch).
    // rank = xcd*50 + bid/8 is a bijection on [0,400); consecutive ranks
    // (the 4 n-siblings of one m-tile) land on one XCD.
    const int rank = (blockIdx.x & 7) * 50 + (blockIdx.x >> 3);
    const int m0 = (rank >> 2) * BM;   // 100 m-blocks
    const int n0 = (rank & 3) * BN;    // 4 n-blocks (rows >=200 masked)

    const int tn = tid & 15;           // output col group
    const int tm = tid >> 4;           // output row group
    const int lr  = tid >> 2;          // W staging row 0..63
    const int lc4 = (tid & 3) * 4;     // W staging k offset {0,4,8,12}
    const int pw  = tid & 31;          // pooling: window col (lane-fastest!)
    const int sub = tid >> 5;          // pooling: 0..7

    float acc[4][4] = {};

    for (int k0 = 0; k0 < PK; k0 += BK) {
        const int ph_base = k0 >> 5;   // even; k-step covers ph_base, ph_base+1
        // ---- stage A tile: 16 pooling windows per thread, coalesced ----
#pragma unroll
        for (int w = 0; w < 16; ++w) {
            int wid = w * 8 + sub;     // 0..127
            int row = wid >> 1;        // bt-row 0..63
            int phh = wid & 1;         // which ph of the two in this k-step
            const float* b0 = x + (long)(m0 + row) * (PH * PW)
                                + (long)(ph_base + phh) * (4 * PW) + pw * 4;
            float s = 0.0f;
#pragma unroll
            for (int i = 0; i < 4; ++i) {
                float4 v = *reinterpret_cast<const float4*>(b0 + i * PW);
                s += v.x + v.y + v.z + v.w;
            }
            Asl[phh * 32 + pw][row] = s * 0.0625f;
        }
        // ---- stage W tile (transpose to k-major, mask rows >= 200) ----
#pragma unroll
        for (int p = 0; p < 4; ++p) {
            int kk = lc4 + p * 16;
            int wrow = n0 + lr;
            float4 v = make_float4(0.f, 0.f, 0.f, 0.f);
            if (wrow < PN)
                v = *reinterpret_cast<const float4*>(&W1[(long)wrow * PK + k0 + kk]);
            Wsl[kk + 0][lr] = v.x; Wsl[kk + 1][lr] = v.y;
            Wsl[kk + 2][lr] = v.z; Wsl[kk + 3][lr] = v.w;
        }
        __syncthreads();
#pragma unroll
        for (int k = 0; k < BK; ++k) {
            float4 av = *reinterpret_cast<const float4*>(&Asl[k][tm * 4]);
            float4 wv = *reinterpret_cast<const float4*>(&Wsl[k][tn * 4]);
            float a_[4] = {av.x, av.y, av.z, av.w};
            float w_[4] = {wv.x, wv.y, wv.z, wv.w};
#pragma unroll
            for (int i = 0; i < 4; ++i)
#pragma unroll
                for (int j = 0; j < 4; ++j)
                    acc[i][j] += a_[i] * w_[j];
        }
        __syncthreads();
    }
    // store (float4 per row; mask per-quad, N=200 divisible by 4)
#pragma unroll
    for (int i = 0; i < 4; ++i) {
        int m = m0 + tm * 4 + i;
        int n = n0 + tn * 4;
        if (n < PN) {
            float4 v = make_float4(acc[i][0], acc[i][1], acc[i][2], acc[i][3]);
            *reinterpret_cast<float4*>(&C[(long)m * PN + n]) = v;
        }
    }
}

// ---------------- Kernel 2: LIF scan + W2 + LI scan ----------------
// g1: [B,T,200], W2: [200], y: [B,T]
__global__ __launch_bounds__(256) void scan_kernel(const float* __restrict__ g1,
                                                   const float* __restrict__ W2,
                                                   float* __restrict__ y) {
    __shared__ float part[PT][4];
    const int b = blockIdx.x;
    const int o = threadIdx.x;
    const int wv = o >> 6;
    const int lane = o & 63;
    const float w2 = (o < PN) ? W2[o] : 0.0f;
    float mem = 0.0f;
    const float* gb = g1 + (long)b * PT * PN;

    for (int t = 0; t < PT; ++t) {
        float g = (o < PN) ? gb[t * PN + o] : 0.0f;
        float reset = (mem > 1.0f) ? 1.0f : 0.0f;
        mem = BETA1 * mem + g - reset;                // THR = 1.0
        float c = ((mem - 1.0f) > 0.0f) ? w2 : 0.0f;  // spike * W2[o]
#pragma unroll
        for (int off = 32; off; off >>= 1)
            c += __shfl_xor(c, off, 64);
        if (lane == 0) part[t][wv] = c;
    }
    __syncthreads();
    if (o == 0) {
        float li = 0.0f;
        for (int t = 0; t < PT; ++t) {
            float g2 = part[t][0] + part[t][1] + part[t][2] + part[t][3];
            li = BETA2 * li + g2;                     // LI never resets (thr=1e5)
            y[b * PT + t] = li;
        }
    }
}

extern "C" void kernel_launch(void* const* d_in, const int* in_sizes, int n_in,
                              void* d_out, int out_size, void* d_ws, size_t ws_size,
                              hipStream_t stream) {
    const float* x  = (const float*)d_in[0];   // [64,100,128,128]
    const float* W1 = (const float*)d_in[1];   // [200,1024]
    const float* W2 = (const float*)d_in[2];   // [1,200]
    float* y = (float*)d_out;                  // [64,100,1]

    float* g1 = (float*)d_ws;                  // 6400*200 f32 = 5.1 MB

    fusedpool_gemm_kernel<<<(PM / BM) * 4, 256, 0, stream>>>(x, W1, g1);
    scan_kernel<<<PB, 256, 0, stream>>>(g1, W2, y);
}

// Round 5
// 631.575 us; speedup vs baseline: 1.6439x; 1.6439x over previous
//
#include <hip/hip_runtime.h>
#include <hip/hip_bf16.h>

// Problem constants
#define PB   64          // batch
#define PT   100         // time steps
#define PH   128         // height
#define PW   128         // width
#define PF   1024        // pooled features = (128/4)*(128/4)
#define PM   (PB*PT)     // 6400 GEMM rows
#define PK   PF          // 1024
#define PN   200         // neurons
#define BETA1 0.95f
#define BETA2 0.9f

typedef float f4v __attribute__((ext_vector_type(4)));

// ---------------- Kernel 1: 4x4 average pooling ----------------
// x: [B,T,128,128] -> xp: [B*T, 1024]  (f = ph*32 + pw)
// Fully coalesced (32 lanes = one contiguous 512B image row per float4 inst).
// Nontemporal x loads: x has zero reuse; keep L3 free so xp stays resident
// for the GEMM that follows.
__global__ __launch_bounds__(256) void pool_kernel(const float* __restrict__ x,
                                                   float* __restrict__ xp) {
    const long total = (long)PM * PF;   // 6,553,600
    for (long idx = (long)blockIdx.x * blockDim.x + threadIdx.x; idx < total;
         idx += (long)gridDim.x * blockDim.x) {
        int f  = (int)(idx & (PF - 1));
        long bt = idx >> 10;
        int ph = f >> 5, pw = f & 31;
        const float* base = x + (bt * PH + ph * 4) * PW + pw * 4;
        float s = 0.0f;
#pragma unroll
        for (int i = 0; i < 4; ++i) {
            f4v v = __builtin_nontemporal_load(
                reinterpret_cast<const f4v*>(base + i * PW));
            s += v.x + v.y + v.z + v.w;   // row-major window order (bitwise-stable)
        }
        xp[idx] = s * 0.0625f;
    }
}

// ---------------- Kernel 2: fp32 GEMM g1 = xp * W1^T ----------------
// A: [6400,1024] (L3-resident), W1: [200,1024] (L2-resident), C: [6400,200]
// BM=64 x BN=32, BK=64, 4x2 microtile, 256 threads -> 700 blocks (2.7/CU,
// ~6 resident/CU by LDS). Pads: A stride 68 floats (16B-aligned b128 reads,
// staging writes 2-way=free), W stride 34 (8B-aligned b64 reads, 2-way=free).
#define BM 64
#define BN 32
#define BK 64
__global__ __launch_bounds__(256) void gemm_kernel(const float* __restrict__ A,
                                                   const float* __restrict__ W1,
                                                   float* __restrict__ C) {
    __shared__ float Asl[BK][BM + 4];   // stride 68: 68*4B=272, %16==0
    __shared__ float Wsl[BK][BN + 2];   // stride 34: 34*4B=136, %8==0
    const int tid = threadIdx.x;

    // Bijective XCD swizzle for 700 blocks (700 = 8*87 + 4):
    // consecutive ranks (the 7 n-siblings of one m-panel) land on one XCD.
    const int xcd  = blockIdx.x & 7;
    const int slot = blockIdx.x >> 3;
    const int base = (xcd < 4) ? xcd * 88 : 4 * 88 + (xcd - 4) * 87;
    const int rank = base + slot;
    const int mblk = rank / 7;            // 0..99
    const int nblk = rank - mblk * 7;     // 0..6
    const int m0 = mblk * BM;
    const int n0 = nblk * BN;

    const int tn = tid & 15;              // cols n0 + tn*2
    const int tm = tid >> 4;              // rows m0 + tm*4
    const int alr = tid >> 2;             // A staging row 0..63
    const int akc = (tid & 3) * 4;        // A staging k offset {0,4,8,12}
    const int wlr = tid & 31;             // W staging row 0..31
    const int wkg = (tid >> 5) * 8;       // W staging k group {0,8,...,56}

    float acc[4][2] = {};

    for (int k0 = 0; k0 < PK; k0 += BK) {
        // stage A tile (transpose to k-major); quad covers 64B contiguous
#pragma unroll
        for (int p = 0; p < 4; ++p) {
            int kk = akc + p * 16;
            float4 v = *reinterpret_cast<const float4*>(
                &A[(long)(m0 + alr) * PK + k0 + kk]);
            Asl[kk + 0][alr] = v.x; Asl[kk + 1][alr] = v.y;
            Asl[kk + 2][alr] = v.z; Asl[kk + 3][alr] = v.w;
        }
        // stage W tile (transpose to k-major, mask rows >= 200)
#pragma unroll
        for (int p = 0; p < 2; ++p) {
            int kk = wkg + p * 4;
            int row = n0 + wlr;
            float4 v = make_float4(0.f, 0.f, 0.f, 0.f);
            if (row < PN)
                v = *reinterpret_cast<const float4*>(&W1[(long)row * PK + k0 + kk]);
            Wsl[kk + 0][wlr] = v.x; Wsl[kk + 1][wlr] = v.y;
            Wsl[kk + 2][wlr] = v.z; Wsl[kk + 3][wlr] = v.w;
        }
        __syncthreads();
#pragma unroll
        for (int k = 0; k < BK; ++k) {
            float4 av = *reinterpret_cast<const float4*>(&Asl[k][tm * 4]);
            float2 wv = *reinterpret_cast<const float2*>(&Wsl[k][tn * 2]);
            acc[0][0] += av.x * wv.x; acc[0][1] += av.x * wv.y;
            acc[1][0] += av.y * wv.x; acc[1][1] += av.y * wv.y;
            acc[2][0] += av.z * wv.x; acc[2][1] += av.z * wv.y;
            acc[3][0] += av.w * wv.x; acc[3][1] += av.w * wv.y;
        }
        __syncthreads();
    }
    // store float2 per row; col is even, N=200 even -> per-pair mask
    const int n = n0 + tn * 2;
    if (n < PN) {
#pragma unroll
        for (int i = 0; i < 4; ++i) {
            int m = m0 + tm * 4 + i;
            float2 v = make_float2(acc[i][0], acc[i][1]);
            *reinterpret_cast<float2*>(&C[(long)m * PN + n]) = v;
        }
    }
}

// ---------------- Kernel 3: LIF scan + W2 + LI scan ----------------
// g1: [B,T,200], W2: [200], y: [B,T]. g-load for t+1 prefetched before the
// shuffle chain of t to hide L2 latency in the serial T-loop.
__global__ __launch_bounds__(256) void scan_kernel(const float* __restrict__ g1,
                                                   const float* __restrict__ W2,
                                                   float* __restrict__ y) {
    __shared__ float part[PT][4];
    const int b = blockIdx.x;
    const int o = threadIdx.x;
    const int wv = o >> 6;
    const int lane = o & 63;
    const float w2 = (o < PN) ? W2[o] : 0.0f;
    float mem = 0.0f;
    const float* gb = g1 + (long)b * PT * PN;

    float gnext = (o < PN) ? gb[o] : 0.0f;
    for (int t = 0; t < PT; ++t) {
        float g = gnext;
        if (t + 1 < PT) gnext = (o < PN) ? gb[(t + 1) * PN + o] : 0.0f;
        float reset = (mem > 1.0f) ? 1.0f : 0.0f;   // reset on PRE-update mem
        mem = BETA1 * mem + g - reset;              // THR = 1.0
        float c = ((mem - 1.0f) > 0.0f) ? w2 : 0.0f;  // spike * W2[o]
#pragma unroll
        for (int off = 32; off; off >>= 1)
            c += __shfl_xor(c, off, 64);
        if (lane == 0) part[t][wv] = c;
    }
    __syncthreads();
    if (o == 0) {
        float li = 0.0f;
        for (int t = 0; t < PT; ++t) {
            float g2 = part[t][0] + part[t][1] + part[t][2] + part[t][3];
            li = BETA2 * li + g2;                   // LI never resets (thr=1e5)
            y[b * PT + t] = li;
        }
    }
}

extern "C" void kernel_launch(void* const* d_in, const int* in_sizes, int n_in,
                              void* d_out, int out_size, void* d_ws, size_t ws_size,
                              hipStream_t stream) {
    const float* x  = (const float*)d_in[0];   // [64,100,128,128]
    const float* W1 = (const float*)d_in[1];   // [200,1024]
    const float* W2 = (const float*)d_in[2];   // [1,200]
    float* y = (float*)d_out;                  // [64,100,1]

    float* xp = (float*)d_ws;                  // 6400*1024 f32 = 26.2 MB
    float* g1 = xp + (long)PM * PF;            // 6400*200  f32 =  5.1 MB

    pool_kernel<<<2048, 256, 0, stream>>>(x, xp);
    gemm_kernel<<<700, 256, 0, stream>>>(xp, W1, g1);
    scan_kernel<<<PB, 256, 0, stream>>>(g1, W2, y);
}